// Round 5
// baseline (286.030 us; speedup 1.0000x reference)
//
#include <hip/hip_runtime.h>
#include <hip/hip_bf16.h>
#include <cstdint>
#include <cstddef>

// B=4, S=2048, D=1024. Inputs fp32 (runtime-detected, bf16 path kept).
// Round-12: attention GEMMs (QK^T, PV) moved to a faithful m201-style 8-phase
// schedule (gemm8p); proj/prep/softmax/LN identical to round-11.
//
// gemm8p: 256x256 tile, 8 waves (2M x 4N), per-wave 128x64 = acc[4][2] of
// 32x32x16 bf16 MFMAs. 2 K64-tiles per iter (buf0=even tile, buf1=odd),
// 8 phases/iter; each phase = {ds_read frags; stage 1 half-tile (2x
// global_load_lds); [vmcnt@ph4/8]; barrier; MFMA quadrant (8); barrier}.
// Half-tiles are CONSUMPTION regions made LDS-contiguous by a row permutation:
//   A phys row p -> global row ((p>>6)&1)<<7 | ((p>>7)&1)<<6 | (p&63)
//     (A-half0 = rows {0-63,128-191} = mi-pair 0/1 for both wm waves)
//   B phys row p -> global ((p>>5)&3)*64 + ((p>>7)&1)*32 + (p&31)
//     (B-half0 = rows {0-31,64-95,128-159,192-223} = ni=0 for all wn)
// Quadrant order (mi01,n0),(mi01,n1),(mi23,n0),(mi23,n1): region last-reads
// at ph1(A01,Bn0), ph2(Bn1), ph3(A23). Stage slots (all >=1 barrier after the
// region's last read -- no latency assumptions):
//   ph1: buf1.A23(T1)   ph2: buf0.A01(T0+2)  ph3: buf0.Bn0  ph4: buf0.Bn1+vm
//   ph5: buf0.A23       ph6: buf1.A01(T1+2)  ph7: buf1.Bn0  ph8: buf1.Bn1+vm
// Ledger: in-flight at ph4/ph8 vmcnt = 7 halves (14 loads); drain to 6 loads
// certifies exactly the 4 halves of the next-to-be-read tile; 3 half-tiles
// stay in flight (T4: counted, never 0 mid-loop).
// Fragment slot map / XOR swizzle / C/D layout verbatim from the verified
// round-9 engine; MFMA accumulation order bit-identical to round-9.
//
// d_ws layout (16B-aligned, ~107 MB):
//   bias5 @ 16           10,240   (bq|bk|bv|gamma|beta bf16)
//   Wt    @ 16,384       6,291,456   ([3][1024][1024]: q,k,v; [d_out][k])
//   QK2   @ 6,307,840    33,554,432  ([8192][2048]: Q|K, later Ctx0|Ctx1)
//   Xb    @ 39,862,272   16,777,216
//   S4/P4 @ 56,639,488   33,554,432
//   Vt    @ 90,193,920   16,777,216  ([1024][8192], batch b at col 2048b)

typedef unsigned short u16;
using bf16x8 = __attribute__((ext_vector_type(8))) short;
using f32x16 = __attribute__((ext_vector_type(16))) float;

typedef __attribute__((address_space(3))) unsigned int lds_uint;
typedef const __attribute__((address_space(1))) unsigned int glob_uint;

__device__ __forceinline__ float bf2f(u16 h) {
    union { unsigned int u; float f; } c;
    c.u = ((unsigned int)h) << 16;
    return c.f;
}
__device__ __forceinline__ u16 f2bf(float f) {
    union { float f; unsigned int u; } c;
    c.f = f;
    return (u16)((c.u + 0x7fffu + ((c.u >> 16) & 1u)) >> 16);  // RNE
}
__device__ __forceinline__ void load_lds16(const void* g, void* l) {
    __builtin_amdgcn_global_load_lds((glob_uint*)g, (lds_uint*)l, 16, 0, 0);
}

#define FENCE asm volatile("" ::: "memory")
#define BARR  do { FENCE; __builtin_amdgcn_s_barrier(); FENCE; } while (0)

// Inline dtype detection: even-index u16s of X decode as bf16 to small finite
// nonzero values iff X is bf16; fp32 mantissa halves produce huge/NaN decodes.
__device__ __forceinline__ int detect_fp32(const u16* X, int* sflag) {
    const int t = threadIdx.x;
    if (t < 64) {
        bool bad = false, nz = false;
#pragma unroll
        for (int j = 0; j < 4; ++j) {
            float v = bf2f(X[(t * 4 + j) * 2]);
            if (!(fabsf(v) <= 1e9f)) bad = true;
            if (v != 0.f) nz = true;
        }
        unsigned long long ab = __ballot(bad);
        unsigned long long an = __ballot(nz);
        if (t == 0) *sflag = (ab != 0ull || an == 0ull) ? 1 : 0;
    }
    __syncthreads();
    return *sflag;
}

// ------------------------------------------------------------------- prep
__global__ __launch_bounds__(256) void prep_kernel(
    const void* __restrict__ X, const void* __restrict__ Wq,
    const void* __restrict__ Wk, const void* __restrict__ Wv,
    const void* __restrict__ bq, const void* __restrict__ bk,
    const void* __restrict__ bv, const void* __restrict__ gamma,
    const void* __restrict__ beta,
    u16* __restrict__ Xb, u16* __restrict__ Wt, u16* __restrict__ bias5)
{
    __shared__ u16 tile[64][72];
    __shared__ int sflag;
    const int fp32 = detect_fp32((const u16*)X, &sflag);
    const int t   = threadIdx.x;
    const int blk = blockIdx.x;

    if (blk < 4096) {                       // ---- convert X
        const size_t i = ((size_t)blk * 256 + t) * 8;
        if (fp32) {
            const float* f = (const float*)X;
            float4 a = *(const float4*)(f + i);
            float4 b = *(const float4*)(f + i + 4);
            ushort4 o0, o1;
            o0.x = f2bf(a.x); o0.y = f2bf(a.y); o0.z = f2bf(a.z); o0.w = f2bf(a.w);
            o1.x = f2bf(b.x); o1.y = f2bf(b.y); o1.z = f2bf(b.z); o1.w = f2bf(b.w);
            *(ushort4*)(Xb + i) = o0;
            *(ushort4*)(Xb + i + 4) = o1;
        } else {
            *(uint4*)(Xb + i) = *(const uint4*)((const u16*)X + i);
        }
    } else if (blk < 4864) {                // ---- transpose W
        const int idx = blk - 4096;
        const int k0 = (idx & 15) * 64;
        const int n0 = ((idx >> 4) & 15) * 64;
        const int w  = idx >> 8;
        const void* W = (w == 0) ? Wq : ((w == 1) ? Wk : Wv);
#pragma unroll
        for (int it = 0; it < 2; ++it) {
            int i2 = t + it * 256;
            int r = i2 >> 3;
            int c = (i2 & 7) * 8;
            const size_t off = (size_t)(k0 + r) * 1024 + n0 + c;
            if (fp32) {
                const float* Wf = (const float*)W + off;
                float4 a = *(const float4*)Wf;
                float4 b = *(const float4*)(Wf + 4);
                u16* tp = &tile[r][c];
                tp[0] = f2bf(a.x); tp[1] = f2bf(a.y); tp[2] = f2bf(a.z); tp[3] = f2bf(a.w);
                tp[4] = f2bf(b.x); tp[5] = f2bf(b.y); tp[6] = f2bf(b.z); tp[7] = f2bf(b.w);
            } else {
                *(uint4*)&tile[r][c] = *(const uint4*)((const u16*)W + off);
            }
        }
        __syncthreads();
#pragma unroll
        for (int it = 0; it < 2; ++it) {
            int i2 = t + it * 256;
            int r = i2 >> 3;
            int c = (i2 & 7) * 8;
            union { u16 s[8]; uint4 v; } tmp;
#pragma unroll
            for (int j = 0; j < 8; ++j) tmp.s[j] = tile[c + j][r];
            *(uint4*)(Wt + (size_t)(w * 1024 + n0 + r) * 1024 + k0 + c) = tmp.v;
        }
    } else {                                // ---- small vectors
        const int v = blk - 4864;
        const void* srcs[5] = {bq, bk, bv, gamma, beta};
        const void* src = srcs[v];
        u16* d = bias5 + (size_t)v * 1024;
        const int i = t * 4;
        if (fp32) {
            const float* f = (const float*)src;
            ushort4 o;
            o.x = f2bf(f[i]); o.y = f2bf(f[i + 1]);
            o.z = f2bf(f[i + 2]); o.w = f2bf(f[i + 3]);
            *(ushort4*)(d + i) = o;
        } else {
            *(ushort4*)(d + i) = *(const ushort4*)((const u16*)src + i);
        }
    }
}

// ------------------------------------------------- proj: QK gemm + V^T gemm
// Round-6 verified gemm128 body (128x128 tile, BK=64, 4 waves x 2x2 32x32x16,
// parity-independent XOR kgroup swizzle). 1536 one-dim blocks:
//   [0,1024):    QK2 = Xb @ Wt(qk)^T + bias[col]   (16 n-tiles x 64 m-tiles)
//   [1024,1536): Vt  = Wvt @ Xb^T   + bias[row]    (64 n-tiles x  8 m-tiles)
__global__ __launch_bounds__(256) void proj_kernel(
    const u16* __restrict__ Xb, const u16* __restrict__ Wt,
    u16* __restrict__ QK2, u16* __restrict__ Vt, const u16* __restrict__ bias5)
{
    __shared__ u16 As[2][128 * 32];
    __shared__ u16 Bs[2][128 * 32];
    const int id   = blockIdx.x;
    const bool vt  = (id >= 1024);
    const u16* A;  const u16* Bt;  u16* C;
    int lda, ldb, ldc, m0, n0;
    if (!vt) {
        A = Xb;  lda = 1024;  Bt = Wt;  ldb = 1024;  C = QK2;  ldc = 2048;
        n0 = (id & 15) * 128;  m0 = (id >> 4) * 128;
    } else {
        const int i2 = id - 1024;
        A = Wt + (size_t)2 * 1024 * 1024;  lda = 1024;   // Wv^T [d][k]
        Bt = Xb;  ldb = 1024;  C = Vt;  ldc = 8192;
        n0 = (i2 & 63) * 128;  m0 = (i2 >> 6) * 128;
    }
    const int t    = threadIdx.x;
    const int lane = t & 63;
    const int w    = t >> 6;
    const int wr   = w >> 1, wc = w & 1;

    // swizzled staging (wave w covers rows [w*32, w*32+32)); key = (srow>>1)&3
    const int srow = lane >> 2;
    const int skg  = (lane & 3) ^ ((srow >> 1) & 3);
    const u16* Ag0 = A  + (size_t)(m0 + w * 32 +      srow) * lda + skg * 8;
    const u16* Ag1 = A  + (size_t)(m0 + w * 32 + 16 + srow) * lda + skg * 8;
    const u16* Bg0 = Bt + (size_t)(n0 + w * 32 +      srow) * ldb + skg * 8;
    const u16* Bg1 = Bt + (size_t)(n0 + w * 32 + 16 + srow) * ldb + skg * 8;
    u16* Al0 = &As[0][(w * 32) * 32];
    u16* Al1 = &As[1][(w * 32) * 32];
    u16* Bl0 = &Bs[0][(w * 32) * 32];
    u16* Bl1 = &Bs[1][(w * 32) * 32];

    f32x16 acc[2][2];
#pragma unroll
    for (int mi = 0; mi < 2; ++mi)
#pragma unroll
        for (int ni = 0; ni < 2; ++ni)
#pragma unroll
            for (int r = 0; r < 16; ++r)
                acc[mi][ni][r] = 0.f;

    const int ml  = lane & 31;
    const int kh  = lane >> 5;
    const int key = (ml >> 1) & 3;

    for (int k0 = 0; k0 < 1024; k0 += 64) {
        load_lds16(Ag0 + k0,      Al0);
        load_lds16(Ag1 + k0,      Al0 + 16 * 32);
        load_lds16(Bg0 + k0,      Bl0);
        load_lds16(Bg1 + k0,      Bl0 + 16 * 32);
        load_lds16(Ag0 + k0 + 32, Al1);
        load_lds16(Ag1 + k0 + 32, Al1 + 16 * 32);
        load_lds16(Bg0 + k0 + 32, Bl1);
        load_lds16(Bg1 + k0 + 32, Bl1 + 16 * 32);
        __syncthreads();
#pragma unroll
        for (int slab = 0; slab < 2; ++slab) {
            const u16* as_ = As[slab];
            const u16* bs_ = Bs[slab];
#pragma unroll
            for (int s = 0; s < 2; ++s) {
                const int g    = s * 2 + kh;
                const int slot = (g ^ key) * 8;
                bf16x8 a0 = *(const bf16x8*)&as_[(wr * 64 +      ml) * 32 + slot];
                bf16x8 a1 = *(const bf16x8*)&as_[(wr * 64 + 32 + ml) * 32 + slot];
                bf16x8 b0 = *(const bf16x8*)&bs_[(wc * 64 +      ml) * 32 + slot];
                bf16x8 b1 = *(const bf16x8*)&bs_[(wc * 64 + 32 + ml) * 32 + slot];
                acc[0][0] = __builtin_amdgcn_mfma_f32_32x32x16_bf16(a0, b0, acc[0][0], 0, 0, 0);
                acc[0][1] = __builtin_amdgcn_mfma_f32_32x32x16_bf16(a0, b1, acc[0][1], 0, 0, 0);
                acc[1][0] = __builtin_amdgcn_mfma_f32_32x32x16_bf16(a1, b0, acc[1][0], 0, 0, 0);
                acc[1][1] = __builtin_amdgcn_mfma_f32_32x32x16_bf16(a1, b1, acc[1][1], 0, 0, 0);
            }
        }
        __syncthreads();
    }

    // C/D layout (m74/m101): col = lane&31, row = (r&3) + 8*(r>>2) + 4*(lane>>5)
    const int colb = n0 + wc * 64 + ml;
    const int rowb = m0 + wr * 64 + 4 * kh;
#pragma unroll
    for (int mi = 0; mi < 2; ++mi) {
#pragma unroll
        for (int ni = 0; ni < 2; ++ni) {
            const int col = colb + ni * 32;
            const float cbias = vt ? 0.f : bf2f(bias5[col]);
#pragma unroll
            for (int r = 0; r < 16; ++r) {
                const int row = rowb + mi * 32 + (r & 3) + 8 * (r >> 2);
                const float bias = vt ? bf2f(bias5[2048 + row]) : cbias;
                C[(size_t)row * ldc + col] = f2bf(acc[mi][ni][r] + bias);
            }
        }
    }
}

// ----------------------------------------- GEMM 256x256, 8-phase (round-12)
template<int KSPLIT>
__global__ __launch_bounds__(512, 2) void gemm8p(
    const u16* __restrict__ A, int lda, size_t sA,
    const u16* __restrict__ Bt, int ldb, size_t sB,
    u16* __restrict__ C, int ldc, size_t sC,
    int K, float scale)
{
    __shared__ u16 As[2][256 * 64];     // 64 KB (2 K-tiles)
    __shared__ u16 Bs[2][256 * 64];     // 64 KB

    const int t  = threadIdx.x;
    const int l  = t & 63;
    const int w  = t >> 6;              // 0..7
    const int wm = w >> 2;              // 0..1
    const int wn = w & 3;               // 0..3
    const int m0 = blockIdx.y * 256;
    const int n0 = blockIdx.x * 256;
    const int batch = (int)blockIdx.z >> (KSPLIT - 1);
    const int ksz   = (int)blockIdx.z & (KSPLIT - 1);
    A  += (size_t)batch * sA + (size_t)ksz * K;
    Bt += (size_t)batch * sB + (size_t)ksz * K;
    C  += (size_t)batch * sC + (size_t)ksz * 1024;   // ksz==0 when KSPLIT==1

    // ---- staging constants (pre-swizzled global source, linear LDS dest)
    const int q   = t >> 3;                 // 0..63 (row within chunk)
    const int sg  = (t & 7) ^ (q & 7);      // k-group for this lane
    const int q5  = (q >> 5) & 1, q31 = q & 31;
    int offA[4], offB[4];
#pragma unroll
    for (int i = 0; i < 4; ++i) {
        const int ga = ((i & 1) << 7) + ((i >> 1) << 6) + q;
        const int gb = ((i & 1) << 7) + ((i >> 1) << 5) + q5 * 64 + q31;
        offA[i] = (m0 + ga) * lda + sg * 8;
        offB[i] = (n0 + gb) * ldb + sg * 8;
    }
    // stage half h of K-tile j into buffer bf (2 x global_load_lds)
    auto stgA = [&](int j, int bf, int h) {
#pragma unroll
        for (int i = 2 * h; i < 2 * h + 2; ++i)
            load_lds16(A + (size_t)offA[i] + j * 64, &As[bf][i * 4096 + w * 512]);
    };
    auto stgB = [&](int j, int bf, int h) {
#pragma unroll
        for (int i = 2 * h; i < 2 * h + 2; ++i)
            load_lds16(Bt + (size_t)offB[i] + j * 64, &Bs[bf][i * 4096 + w * 512]);
    };

    // ---- read-side constants (phys-row layout per the header permutation)
    const int lr = l & 31, kh = l >> 5;
    const int keyr = lr & 7;
    int arow[4], slot[4];
#pragma unroll
    for (int mi = 0; mi < 4; ++mi)
        arow[mi] = ((mi >> 1) * 128 + wm * 64 + (mi & 1) * 32 + lr) * 64;
    const int brow0 = (wn * 32 + lr) * 64;          // ni=0
    const int brow1 = (128 + wn * 32 + lr) * 64;    // ni=1
#pragma unroll
    for (int kk = 0; kk < 4; ++kk)
        slot[kk] = ((2 * kk + kh) ^ keyr) * 8;

    auto rdA = [&](bf16x8 (&d)[4], int mi, int bf) {
#pragma unroll
        for (int kk = 0; kk < 4; ++kk)
            d[kk] = *(const bf16x8*)&As[bf][arow[mi] + slot[kk]];
    };
    auto rdB = [&](bf16x8 (&d)[4], int br, int bf) {
#pragma unroll
        for (int kk = 0; kk < 4; ++kk)
            d[kk] = *(const bf16x8*)&Bs[bf][br + slot[kk]];
    };

    f32x16 acc[4][2];
#pragma unroll
    for (int mi = 0; mi < 4; ++mi)
#pragma unroll
        for (int ni = 0; ni < 2; ++ni)
#pragma unroll
            for (int r = 0; r < 16; ++r) acc[mi][ni][r] = 0.f;

#define QUAD8(A0_, A1_, B_, ALO, AHI)                                            \
    __builtin_amdgcn_s_setprio(1);                                               \
    _Pragma("unroll")                                                            \
    for (int kq = 0; kq < 4; ++kq) {                                             \
        ALO = __builtin_amdgcn_mfma_f32_32x32x16_bf16(A0_[kq], B_[kq], ALO, 0, 0, 0); \
        AHI = __builtin_amdgcn_mfma_f32_32x32x16_bf16(A1_[kq], B_[kq], AHI, 0, 0, 0); \
    }                                                                            \
    __builtin_amdgcn_s_setprio(0);

    const int NS = K >> 6;              // even (K = 1024/2048)
    const int iters = NS >> 1;

    // prologue: tile0 (buf0, 4 halves) + tile1 (buf1, 3 halves); certify tile0
    stgA(0, 0, 0); stgB(0, 0, 0); stgB(0, 0, 1); stgA(0, 0, 1);
    stgA(1, 1, 0); stgB(1, 1, 0); stgB(1, 1, 1);
    asm volatile("s_waitcnt vmcnt(6)" ::: "memory");
    BARR;

    for (int i = 0; i < iters; ++i) {
        const int T0 = 2 * i, T1 = 2 * i + 1;
        const bool more = (i + 1 < iters);
        bf16x8 a0[4], a1[4], b0[4], b1[4];
        // ph1: (mi01, n0) on buf0 | stage buf1.A23(T1)
        rdA(a0, 0, 0); rdA(a1, 1, 0); rdB(b0, brow0, 0);
        stgA(T1, 1, 1);
        BARR;
        QUAD8(a0, a1, b0, acc[0][0], acc[1][0]);
        BARR;
        // ph2: (mi01, n1) | stage buf0.A01(T0+2)
        rdB(b1, brow1, 0);
        if (more) stgA(T0 + 2, 0, 0);
        BARR;
        QUAD8(a0, a1, b1, acc[0][1], acc[1][1]);
        BARR;
        // ph3: (mi23, n0) | stage buf0.Bn0(T0+2)
        rdA(a0, 2, 0); rdA(a1, 3, 0);
        if (more) stgB(T0 + 2, 0, 0);
        BARR;
        QUAD8(a0, a1, b0, acc[2][0], acc[3][0]);
        BARR;
        // ph4: (mi23, n1) | stage buf0.Bn1(T0+2) | vmcnt certifies tile T1
        if (more) stgB(T0 + 2, 0, 1);
        if (more) asm volatile("s_waitcnt vmcnt(6)" ::: "memory");
        else      asm volatile("s_waitcnt vmcnt(0)" ::: "memory");
        BARR;
        QUAD8(a0, a1, b1, acc[2][1], acc[3][1]);
        BARR;
        // ph5: (mi01, n0) on buf1 | stage buf0.A23(T0+2)
        rdA(a0, 0, 1); rdA(a1, 1, 1); rdB(b0, brow0, 1);
        if (more) stgA(T0 + 2, 0, 1);
        BARR;
        QUAD8(a0, a1, b0, acc[0][0], acc[1][0]);
        BARR;
        // ph6: (mi01, n1) | stage buf1.A01(T1+2)
        rdB(b1, brow1, 1);
        if (more) stgA(T1 + 2, 1, 0);
        BARR;
        QUAD8(a0, a1, b1, acc[0][1], acc[1][1]);
        BARR;
        // ph7: (mi23, n0) | stage buf1.Bn0(T1+2)
        rdA(a0, 2, 1); rdA(a1, 3, 1);
        if (more) stgB(T1 + 2, 1, 0);
        BARR;
        QUAD8(a0, a1, b0, acc[2][0], acc[3][0]);
        BARR;
        // ph8: (mi23, n1) | stage buf1.Bn1(T1+2) | vmcnt certifies tile T0+2
        if (more) stgB(T1 + 2, 1, 1);
        if (more) asm volatile("s_waitcnt vmcnt(6)" ::: "memory");
        else      asm volatile("s_waitcnt vmcnt(0)" ::: "memory");
        BARR;
        QUAD8(a0, a1, b1, acc[2][1], acc[3][1]);
        BARR;
    }
#undef QUAD8

    // epilogue: C/D layout (m74/m101)
    const int colb = n0 + wn * 64 + lr;
    const int rowb = m0 + wm * 128 + 4 * kh;
#pragma unroll
    for (int mi = 0; mi < 4; ++mi) {
#pragma unroll
        for (int ni = 0; ni < 2; ++ni) {
            const int col = colb + ni * 32;
#pragma unroll
            for (int r = 0; r < 16; ++r) {
                const int row = rowb + mi * 32 + (r & 3) + 8 * (r >> 2);
                C[(size_t)row * ldc + col] = f2bf(acc[mi][ni][r] * scale);
            }
        }
    }
}

// ----------------------------------------------------------- softmax (bf16)
__global__ __launch_bounds__(256) void softmax_bf16_kernel(u16* __restrict__ S)
{
    const int t = threadIdx.x;
    u16* sp = S + (size_t)blockIdx.x * 2048;
    union { uint4 v; u16 h[8]; } raw;
    raw.v = *(const uint4*)(sp + t * 8);
    float vals[8];
#pragma unroll
    for (int i = 0; i < 8; ++i) vals[i] = bf2f(raw.h[i]);
    float m = vals[0];
#pragma unroll
    for (int i = 1; i < 8; ++i) m = fmaxf(m, vals[i]);
#pragma unroll
    for (int off = 32; off > 0; off >>= 1) m = fmaxf(m, __shfl_xor(m, off));
    __shared__ float red[8];
    const int w = t >> 6, lane = t & 63;
    if (lane == 0) red[w] = m;
    __syncthreads();
    m = fmaxf(fmaxf(red[0], red[1]), fmaxf(red[2], red[3]));
    float e[8], s = 0.f;
#pragma unroll
    for (int i = 0; i < 8; ++i) { e[i] = __expf(vals[i] - m); s += e[i]; }
#pragma unroll
    for (int off = 32; off > 0; off >>= 1) s += __shfl_xor(s, off);
    if (lane == 0) red[4 + w] = s;
    __syncthreads();
    s = red[4] + red[5] + red[6] + red[7];
    const float rinv = 1.f / s;
    union { uint4 v; u16 h[8]; } out;
#pragma unroll
    for (int i = 0; i < 8; ++i) out.h[i] = f2bf(e[i] * rinv);
    *(uint4*)(sp + t * 8) = out.v;
}

// ---------------------------------------------------------------- resid + LN
// Ctx is split across the Q-slot (cols 0..1023) and K-slot (cols 1024..2047)
// of QK2 (PV split-K2 partial sums); sum both halves here.
__global__ __launch_bounds__(256) void resid_ln_kernel(
    const u16* __restrict__ Ctx, const u16* __restrict__ Xb,
    const u16* __restrict__ gamma, const u16* __restrict__ beta,
    void* __restrict__ Out, const u16* __restrict__ Xraw)
{
    __shared__ int sflag;
    const int fp32 = detect_fp32(Xraw, &sflag);
    const size_t row = blockIdx.x;
    const int t = threadIdx.x;
    ushort4 cv0 = *(const ushort4*)(Ctx + row * 2048 + t * 4);
    ushort4 cv1 = *(const ushort4*)(Ctx + row * 2048 + 1024 + t * 4);
    ushort4 xv  = *(const ushort4*)(Xb + row * 1024 + t * 4);
    float v[4] = {bf2f(cv0.x) + bf2f(cv1.x) + bf2f(xv.x),
                  bf2f(cv0.y) + bf2f(cv1.y) + bf2f(xv.y),
                  bf2f(cv0.z) + bf2f(cv1.z) + bf2f(xv.z),
                  bf2f(cv0.w) + bf2f(cv1.w) + bf2f(xv.w)};
    float s  = v[0] + v[1] + v[2] + v[3];
    float s2 = v[0] * v[0] + v[1] * v[1] + v[2] * v[2] + v[3] * v[3];
#pragma unroll
    for (int off = 32; off > 0; off >>= 1) {
        s  += __shfl_xor(s, off);
        s2 += __shfl_xor(s2, off);
    }
    __shared__ float red[8];
    const int w = t >> 6, lane = t & 63;
    if (lane == 0) { red[w] = s; red[4 + w] = s2; }
    __syncthreads();
    s  = red[0] + red[1] + red[2] + red[3];
    s2 = red[4] + red[5] + red[6] + red[7];
    const float mu  = s * (1.f / 1024.f);
    const float var = s2 * (1.f / 1024.f) - mu * mu;
    const float inv = rsqrtf(var + 1e-3f);
    ushort4 gv = *(const ushort4*)(gamma + t * 4);
    ushort4 bv = *(const ushort4*)(beta + t * 4);
    float o[4];
    o[0] = (v[0] - mu) * inv * bf2f(gv.x) + bf2f(bv.x);
    o[1] = (v[1] - mu) * inv * bf2f(gv.y) + bf2f(bv.y);
    o[2] = (v[2] - mu) * inv * bf2f(gv.z) + bf2f(bv.z);
    o[3] = (v[3] - mu) * inv * bf2f(gv.w) + bf2f(bv.w);
    if (fp32) {
        float4 fo = {o[0], o[1], o[2], o[3]};
        *(float4*)((float*)Out + row * 1024 + t * 4) = fo;
    } else {
        ushort4 bo;
        bo.x = f2bf(o[0]); bo.y = f2bf(o[1]); bo.z = f2bf(o[2]); bo.w = f2bf(o[3]);
        *(ushort4*)((u16*)Out + row * 1024 + t * 4) = bo;
    }
}

// ---------------------------------------------------------------- launch
extern "C" void kernel_launch(void* const* d_in, const int* in_sizes, int n_in,
                              void* d_out, int out_size, void* d_ws, size_t ws_size,
                              hipStream_t stream)
{
    (void)in_sizes; (void)n_in; (void)out_size; (void)ws_size;
    const void* X     = d_in[0];
    const void* Wq    = d_in[1];
    const void* bq    = d_in[2];
    const void* Wk    = d_in[3];
    const void* bk    = d_in[4];
    const void* Wv    = d_in[5];
    const void* bv    = d_in[6];
    const void* gamma = d_in[7];
    const void* beta  = d_in[8];

    char* ws = (char*)d_ws;
    u16* bias5 = (u16*)(ws + 16);
    u16* Wt    = (u16*)(ws + 16384);
    u16* QK2   = (u16*)(ws + 6307840);
    u16* Xb    = (u16*)(ws + 39862272);
    u16* S4    = (u16*)(ws + 56639488);
    u16* Vt    = (u16*)(ws + 90193920);

    // 1. fused prologue
    prep_kernel<<<4869, 256, 0, stream>>>(
        X, Wq, Wk, Wv, bq, bk, bv, gamma, beta, Xb, Wt, bias5);

    // 2. proj: QK2 = Xb @ Wt(qk)^T + [bq|bk]  (1024 blocks)
    //          Vt  = Wv^T @ Xb^T + bv          (512 blocks)  -> 6 exact rounds
    proj_kernel<<<1536, 256, 0, stream>>>(Xb, Wt, QK2, Vt, bias5);

    // 3. S4[b] = (Q_b @ K_b^T)/32   (M=N=2048, K=1024, z=4) -> 256 blocks
    gemm8p<1><<<dim3(8, 8, 4), 512, 0, stream>>>(
        QK2, 2048, (size_t)2048 * 2048,
        QK2 + 1024, 2048, (size_t)2048 * 2048,
        S4, 2048, (size_t)2048 * 2048, 1024, 0.03125f);

    // 4. softmax
    softmax_bf16_kernel<<<8192, 256, 0, stream>>>(S4);

    // 5. Ctx_b = P_b @ V_b, split-K2 -> Q-slot (ks=0) + K-slot (ks=1) of QK2
    //    (M=2048, N=1024, K=1024 per half, z = 4 x 2) -> 256 blocks
    gemm8p<2><<<dim3(4, 8, 8), 512, 0, stream>>>(
        S4, 2048, (size_t)2048 * 2048,
        Vt, 8192, (size_t)2048,
        QK2, 2048, (size_t)2048 * 2048, 1024, 1.f);

    // 6. LN (sums the two Ctx halves)
    resid_ln_kernel<<<8192, 256, 0, stream>>>(
        QK2, Xb, bias5 + 3 * 1024, bias5 + 4 * 1024, d_out, (const u16*)X);
}